// Round 8
// baseline (52447.357 us; speedup 1.0000x reference)
//
#include <hip/hip_runtime.h>
#include <math.h>

// ---------------------------------------------------------------------------
// GameProcessor round 8: r7 structure (3 rounds/level, fence barrier) with
// doubled thread-level parallelism to hide LLC latency inside rounds:
//  * 512 blocks x 1024 threads, 2 blocks/CU (__launch_bounds__(1024,8),
//    VGPR<=64, LDS ~25KB/block) -> 32 waves/CU, co-residency guaranteed
//    (512 = 256 CU x 2).
//  * block b owns ONE output dim d0=b; hidden unit (r_b=(b>>7)&1, h_b=b&127)
//    is duplicated by blocks b and b+256 (identical value, benign dup store).
//  * barrier: distributed sense-epoch; go-word replicated on 8 lines
//    (poll goRep[b&7], likely XCD-local line) + tight go spin.
//  * phases identical to r7: A (proj both rows + gh-stash, weights read once),
//    C (gates+B1 from ctx only), D (imp, blend, LN, emb write). All fp32.
// ---------------------------------------------------------------------------

#define NG   30000
#define NT   364
#define ND   512
#define NF   28
#define NH   128
#define NCIN 1053
#define NB   512
#define BLK  1024
#define WCAP 192   // > max level width (<=182)

__device__ __forceinline__ float sigmf(float x) { return 1.0f / (1.0f + expf(-x)); }

__device__ __forceinline__ void astore_f(float* p, float v) {
  __hip_atomic_store(p, v, __ATOMIC_RELAXED, __HIP_MEMORY_SCOPE_AGENT);
}
__device__ __forceinline__ void astore_f2(float* p, float x, float y) {
  float2 v = make_float2(x, y);
  unsigned long long u; __builtin_memcpy(&u, &v, 8);
  __hip_atomic_store((unsigned long long*)p, u, __ATOMIC_RELAXED, __HIP_MEMORY_SCOPE_AGENT);
}

__global__ void zero_kernel(int* p, int n) {
  int i = blockIdx.x * blockDim.x + threadIdx.x;
  if (i < n) p[i] = 0;
}

__global__ void deps_kernel(const int* __restrict__ ta, const int* __restrict__ tb,
                            int* __restrict__ dep0, int* __restrict__ dep1) {
  int g = blockIdx.x * blockDim.x + threadIdx.x;
  if (g >= NG) return;
  int a = ta[g], b = tb[g];
  int d0 = -1, d1 = -1;
  for (int p = g - 1; p >= 0; --p) {
    int pa = ta[p], pb = tb[p];
    if (d0 < 0 && (pa == a || pb == a)) d0 = p;
    if (d1 < 0 && (pa == b || pb == b)) d1 = p;
    if (d0 >= 0 && d1 >= 0) break;
  }
  dep0[g] = d0;
  dep1[g] = d1;
}

__global__ void levels_kernel(const int* __restrict__ d0a, const int* __restrict__ d1a,
                              int* __restrict__ level, int* __restrict__ nLevels) {
  __shared__ int lv[1024];
  __shared__ int changed;
  __shared__ int smax;
  const int tid = threadIdx.x;
  int localMax = 0;
  if (tid == 0) smax = 0;
  for (int base = 0; base < NG; base += 1024) {
    const int g = base + tid;
    const bool val = g < NG;
    int ic0 = -1, ic1 = -1, b = 0;
    if (val) {
      int d0 = d0a[g], d1 = d1a[g];
      if (d0 >= 0) { if (d0 < base) b = max(b, level[d0] + 1); else ic0 = d0 - base; }
      if (d1 >= 0) { if (d1 < base) b = max(b, level[d1] + 1); else ic1 = d1 - base; }
    }
    lv[tid] = b;
    __syncthreads();
    for (;;) {
      if (tid == 0) changed = 0;
      __syncthreads();
      int nl = lv[tid];
      if (ic0 >= 0) nl = max(nl, lv[ic0] + 1);
      if (ic1 >= 0) nl = max(nl, lv[ic1] + 1);
      if (val && nl != lv[tid]) { lv[tid] = nl; changed = 1; }
      __syncthreads();
      if (!changed) break;
    }
    if (val) { level[g] = lv[tid]; localMax = max(localMax, lv[tid]); }
    __syncthreads();
  }
  atomicMax(&smax, localMax);
  __syncthreads();
  if (tid == 0) nLevels[0] = smax + 1;
}

__global__ void sort_kernel(const int* __restrict__ level, const int* __restrict__ nLevels,
                            int* __restrict__ hist, int* __restrict__ cursor,
                            int* __restrict__ levelStart, int* __restrict__ levelList) {
  const int tid = threadIdx.x;
  const int nL = nLevels[0];
  for (int i = tid; i < NG; i += 1024) { hist[i] = 0; cursor[i] = 0; }
  __syncthreads();
  for (int g = tid; g < NG; g += 1024) atomicAdd(&hist[level[g]], 1);
  __syncthreads();
  if (tid == 0) {
    int acc = 0;
    for (int i = 0; i < nL; ++i) { levelStart[i] = acc; acc += hist[i]; }
    levelStart[nL] = acc;
  }
  __syncthreads();
  for (int g = tid; g < NG; g += 1024) {
    int l = level[g];
    int off = atomicAdd(&cursor[l], 1);
    levelList[levelStart[l] + off] = g;
  }
}

// Distributed sense-epoch grid barrier with acquire fence.
// goRep: 8 replicated go-lines (128B apart); block b polls goRep[(b&7)*32].
__device__ __forceinline__ void grid_bar(int* goRep, int* arr, int& epoch) {
  ++epoch;
  __syncthreads();
  if (blockIdx.x == 0) {
    const int t = threadIdx.x;
    if (t >= 1 && t < NB) {
      while (__hip_atomic_load(arr + t * 32, __ATOMIC_RELAXED, __HIP_MEMORY_SCOPE_AGENT) < epoch)
        __builtin_amdgcn_s_sleep(1);
    }
    __builtin_amdgcn_fence(__ATOMIC_ACQUIRE, "agent");
    __syncthreads();
    if (t < 8)
      __hip_atomic_store(goRep + t * 32, epoch, __ATOMIC_RELEASE, __HIP_MEMORY_SCOPE_AGENT);
  } else {
    if (threadIdx.x == 0) {
      __hip_atomic_store(arr + blockIdx.x * 32, epoch, __ATOMIC_RELEASE, __HIP_MEMORY_SCOPE_AGENT);
      int* goMine = goRep + (blockIdx.x & 7) * 32;
      while (__hip_atomic_load(goMine, __ATOMIC_RELAXED, __HIP_MEMORY_SCOPE_AGENT) < epoch) { }
      __builtin_amdgcn_fence(__ATOMIC_ACQUIRE, "agent");
    }
    __syncthreads();
  }
}

__global__ __launch_bounds__(BLK, 8)
void game_kernel(const float* __restrict__ Wp,   const float* __restrict__ bp,
                 const float* __restrict__ W_ih, const float* __restrict__ b_ih,
                 const float* __restrict__ W_hh, const float* __restrict__ b_hh,
                 const float* __restrict__ ln_g, const float* __restrict__ ln_b,
                 const float* __restrict__ Wi1,  const float* __restrict__ bi1,
                 const float* __restrict__ Wi2,  const float* __restrict__ bi2,
                 const float* __restrict__ fA,   const float* __restrict__ fB,
                 const int* __restrict__ team_a, const int* __restrict__ team_b,
                 const int* __restrict__ a_won,
                 float* __restrict__ emb, float* __restrict__ ctx,
                 const int* __restrict__ levelStart, const int* __restrict__ levelList,
                 const int* __restrict__ nLevels,
                 float* __restrict__ nhbuf, float* __restrict__ hidbuf,
                 int* __restrict__ goRep, int* __restrict__ arr, int Wcap) {
  const int b    = blockIdx.x;
  const int tid  = threadIdx.x;
  const int lane = tid & 63;
  const int wave = tid >> 6;
  const int grpq = lane >> 4;     // 16-lane group id within wave (0..3)
  const int l4   = lane & 15;
  const int d0   = b;             // owned output dim
  const int r_b  = (b >> 7) & 1;  // owned hidden unit (duplicated by b, b+256)
  const int h_b  = b & 127;

  // ---- LDS: fp32 weights for dim d0, float2-packed {e0,e1} per pair ----
  __shared__ float2 wpS2[256];        // Wp cols 0..511   (e_self)
  __shared__ float2 wpO2[256];        // Wp cols 512..1023 (e_opp)
  __shared__ float  wpT1[32];         // Wp cols 1024..1052
  __shared__ float2 wih2[768];        // W_ih [gate*256 + pair]
  __shared__ float2 whh2[768];        // W_hh
  __shared__ float2 wi12[256];        // Wi1[h_b] pairs
  __shared__ float4 sStash[WCAP][2];  // per game,row: {ghr, ghz, ghn, e_self[d0]}
  __shared__ float sImp[2];
  __shared__ float sRed[2][16];
  __shared__ float sStat[4];

  if (tid < 256) {
    const int p = tid;
    wpS2[p] = make_float2(Wp[(size_t)d0 * NCIN + 2 * p],
                          Wp[(size_t)d0 * NCIN + 2 * p + 1]);
    wpO2[p] = make_float2(Wp[(size_t)d0 * NCIN + ND + 2 * p],
                          Wp[(size_t)d0 * NCIN + ND + 2 * p + 1]);
    wi12[p] = make_float2(Wi1[(size_t)h_b * ND + 2 * p],
                          Wi1[(size_t)h_b * ND + 2 * p + 1]);
  } else if (tid < 288) {
    const int t = tid - 256;
    wpT1[t] = (t < NF + 1) ? Wp[(size_t)d0 * NCIN + 2 * ND + t] : 0.f;
  }
  if (tid < 768) {
    const int gt = tid >> 8, p = tid & 255;
    wih2[tid] = make_float2(W_ih[((size_t)gt * ND + d0) * ND + 2 * p],
                            W_ih[((size_t)gt * ND + d0) * ND + 2 * p + 1]);
    whh2[tid] = make_float2(W_hh[((size_t)gt * ND + d0) * ND + 2 * p],
                            W_hh[((size_t)gt * ND + d0) * ND + 2 * p + 1]);
  }

  const float bp0 = bp[d0];
  float bih[3], bhh[3];
#pragma unroll
  for (int gt = 0; gt < 3; ++gt) {
    bih[gt] = b_ih[gt * ND + d0];
    bhh[gt] = b_hh[gt * ND + d0];
  }
  const float bi1h = bi1[h_b];
  const float bi2v = bi2[0];
  const float2 w2p = ((const float2*)Wi2)[lane];
  float2 lg2 = make_float2(0.f, 0.f), lb2 = lg2;
  if (tid < 512) {
    lg2 = ((const float2*)ln_g)[tid & 255];
    lb2 = ((const float2*)ln_b)[tid & 255];
  }
  __syncthreads();

  const int nL = nLevels[0];
  int epoch = 0;
  const int pairD = d0 >> 1;        // which pair holds e_self[d0]
  const int elemD = d0 & 1;

  for (int L = 0; L < nL; ++L) {
    const int s = levelStart[L], e_ = levelStart[L + 1];
    for (int cs = s; cs < e_; cs += Wcap) {
      const int W = min(e_ - cs, Wcap);

      // ===== R1: phase A (proj both rows -> ctx; gh + e_self -> stash) =====
      for (int w = wave * 4 + grpq; w < W; w += 64) {
        const int g = levelList[cs + w];
        const int ta = team_a[g], tb = team_b[g];
        const float aw = (float)a_won[g];
        const float* rowA = emb + (size_t)ta * ND;
        const float* rowB = emb + (size_t)tb * ND;
        // acc: [0]=proj r0, [1]=proj r1, [2+gt]=gh r0, [5+gt]=gh r1
        float acc[8];
#pragma unroll
        for (int i = 0; i < 8; ++i) acc[i] = 0.f;
        float es0 = 0.f, es1 = 0.f;
#pragma unroll 4
        for (int j = 0; j < 16; ++j) {
          const int p = j * 16 + l4;
          const float2 va = *(const float2*)(rowA + 2 * p);
          const float2 vb = *(const float2*)(rowB + 2 * p);
          const float2 wS = wpS2[p];
          const float2 wO = wpO2[p];
          acc[0] += va.x * wS.x + va.y * wS.y + vb.x * wO.x + vb.y * wO.y;
          acc[1] += vb.x * wS.x + vb.y * wS.y + va.x * wO.x + va.y * wO.y;
#pragma unroll
          for (int gt = 0; gt < 3; ++gt) {
            const float2 q = whh2[gt * 256 + p];
            acc[2 + gt] += va.x * q.x + va.y * q.y;
            acc[5 + gt] += vb.x * q.x + vb.y * q.y;
          }
          if (p == pairD) {
            es0 = elemD ? va.y : va.x;
            es1 = elemD ? vb.y : vb.x;
          }
        }
        // tail cols 1024..1052 over 16 lanes (2 passes)
#pragma unroll
        for (int j = 0; j < 2; ++j) {
          const int t = j * 16 + l4;
          if (t < NF + 1) {
            const float cv0 = (t < NF) ? fA[(size_t)g * NF + t] : aw;
            const float cv1 = (t < NF) ? fB[(size_t)g * NF + t] : 1.0f - aw;
            const float wt = wpT1[t];
            acc[0] += cv0 * wt;
            acc[1] += cv1 * wt;
          }
        }
#pragma unroll
        for (int off = 8; off > 0; off >>= 1) {
#pragma unroll
          for (int i = 0; i < 8; ++i) acc[i] += __shfl_xor(acc[i], off);
          es0 += __shfl_xor(es0, off);
          es1 += __shfl_xor(es1, off);
        }
        if (l4 == 0) {
          astore_f(ctx + (size_t)g * 1024 + d0, fmaxf(acc[0] + bp0, 0.f));
          astore_f(ctx + (size_t)g * 1024 + ND + d0, fmaxf(acc[1] + bp0, 0.f));
          sStash[w][0] = make_float4(acc[2], acc[3], acc[4], es0);
          sStash[w][1] = make_float4(acc[5], acc[6], acc[7], es1);
        }
      }
      grid_bar(goRep, arr, epoch);

      // ===== R2: phase C (gates -> nh, both rows) + B1 (hidden) =====
      for (int w = wave * 4 + grpq; w < W; w += 64) {
        const int g = levelList[cs + w];
        const float* p0 = ctx + (size_t)g * 1024;
        const float* p1 = p0 + ND;
        // acc: [gt]=gi r0, [3+gt]=gi r1, [6]=hidden
        float acc[7];
#pragma unroll
        for (int i = 0; i < 7; ++i) acc[i] = 0.f;
#pragma unroll 4
        for (int j = 0; j < 16; ++j) {
          const int p = j * 16 + l4;
          const float2 x0 = *(const float2*)(p0 + 2 * p);
          const float2 x1 = *(const float2*)(p1 + 2 * p);
#pragma unroll
          for (int gt = 0; gt < 3; ++gt) {
            const float2 q = wih2[gt * 256 + p];
            acc[gt]     += x0.x * q.x + x0.y * q.y;
            acc[3 + gt] += x1.x * q.x + x1.y * q.y;
          }
          const float2 wi = wi12[p];
          const float2 xr = r_b ? x1 : x0;
          acc[6] += xr.x * wi.x + xr.y * wi.y;
        }
#pragma unroll
        for (int off = 8; off > 0; off >>= 1) {
#pragma unroll
          for (int i = 0; i < 7; ++i) acc[i] += __shfl_xor(acc[i], off);
        }
        if (l4 == 0) {
          const float4 s0 = sStash[w][0], s1 = sStash[w][1];
          {
            const float r = sigmf(acc[0] + bih[0] + s0.x + bhh[0]);
            const float z = sigmf(acc[1] + bih[1] + s0.y + bhh[1]);
            const float n = tanhf(acc[2] + bih[2] + r * (s0.z + bhh[2]));
            astore_f(nhbuf + (size_t)w * 1024 + d0, (1.f - z) * n + z * s0.w);
          }
          {
            const float r = sigmf(acc[3] + bih[0] + s1.x + bhh[0]);
            const float z = sigmf(acc[4] + bih[1] + s1.y + bhh[1]);
            const float n = tanhf(acc[5] + bih[2] + r * (s1.z + bhh[2]));
            astore_f(nhbuf + (size_t)w * 1024 + ND + d0, (1.f - z) * n + z * s1.w);
          }
          astore_f(hidbuf + (size_t)w * 256 + r_b * NH + h_b,
                   fmaxf(acc[6] + bi1h, 0.f));
        }
      }
      grid_bar(goRep, arr, epoch);

      // ===== R3: phase D (whole block per game): imp, blend, LN, write =====
      for (int w = b; w < W; w += NB) {
        const int g = levelList[cs + w];
        const int ta = team_a[g], tb = team_b[g];
        if (wave < 2) {
          const float2 hv = *(const float2*)(hidbuf + (size_t)w * 256 + wave * NH + 2 * lane);
          float a = hv.x * w2p.x + hv.y * w2p.y;
#pragma unroll
          for (int off = 32; off > 0; off >>= 1) a += __shfl_xor(a, off);
          if (lane == 0) sImp[wave] = sigmf(a + bi2v);
        }
        __syncthreads();
        float ux = 0.f, uy = 0.f;
        if (tid < 512) {
          const int row = tid >> 8;
          const int e = 2 * (tid & 255);
          const int team = row ? tb : ta;
          const float imp = sImp[row];
          const float2 ev = *(const float2*)(emb + (size_t)team * ND + e);
          const float2 nv = *(const float2*)(nhbuf + (size_t)w * 1024 + (size_t)row * ND + e);
          ux = ev.x + imp * (nv.x - ev.x);
          uy = ev.y + imp * (nv.y - ev.y);
        }
        float sS = ux + uy, sQ = ux * ux + uy * uy;
#pragma unroll
        for (int off = 32; off > 0; off >>= 1) {
          sS += __shfl_xor(sS, off);
          sQ += __shfl_xor(sQ, off);
        }
        if (lane == 0) { sRed[0][wave] = sS; sRed[1][wave] = sQ; }
        __syncthreads();
        if (tid == 0) {
          const float S0 = sRed[0][0] + sRed[0][1] + sRed[0][2] + sRed[0][3];
          const float Q0 = sRed[1][0] + sRed[1][1] + sRed[1][2] + sRed[1][3];
          const float S1 = sRed[0][4] + sRed[0][5] + sRed[0][6] + sRed[0][7];
          const float Q1 = sRed[1][4] + sRed[1][5] + sRed[1][6] + sRed[1][7];
          const float mu0 = S0 * (1.0f / ND), mu1 = S1 * (1.0f / ND);
          const float v0 = Q0 * (1.0f / ND) - mu0 * mu0;
          const float v1 = Q1 * (1.0f / ND) - mu1 * mu1;
          sStat[0] = mu0; sStat[1] = 1.0f / sqrtf(v0 + 1e-5f);
          sStat[2] = mu1; sStat[3] = 1.0f / sqrtf(v1 + 1e-5f);
        }
        __syncthreads();
        if (tid < 512) {
          const int row = tid >> 8;
          const int e = 2 * (tid & 255);
          const float mu = sStat[row * 2], rs = sStat[row * 2 + 1];
          const float ox = (ux - mu) * rs * lg2.x + lb2.x;
          const float oy = (uy - mu) * rs * lg2.y + lb2.y;
          if (row == 0) {
            if (ta != tb) astore_f2(emb + (size_t)ta * ND + e, ox, oy);
          } else {
            astore_f2(emb + (size_t)tb * ND + e, ox, oy);
          }
        }
        __syncthreads();
      }
      grid_bar(goRep, arr, epoch);
    }
  }
}

extern "C" void kernel_launch(void* const* d_in, const int* in_sizes, int n_in,
                              void* d_out, int out_size, void* d_ws, size_t ws_size,
                              hipStream_t stream) {
  const float* emb_table = (const float*)d_in[0];
  const float* Wp    = (const float*)d_in[1];
  const float* bp    = (const float*)d_in[2];
  const float* W_ih  = (const float*)d_in[3];
  const float* b_ih  = (const float*)d_in[4];
  const float* W_hh  = (const float*)d_in[5];
  const float* b_hh  = (const float*)d_in[6];
  const float* ln_g  = (const float*)d_in[7];
  const float* ln_b  = (const float*)d_in[8];
  const float* Wi1   = (const float*)d_in[9];
  const float* bi1   = (const float*)d_in[10];
  const float* Wi2   = (const float*)d_in[11];
  const float* bi2   = (const float*)d_in[12];
  const float* fA    = (const float*)d_in[13];
  const float* fB    = (const float*)d_in[14];
  const int*   team_a = (const int*)d_in[15];
  const int*   team_b = (const int*)d_in[16];
  const int*   a_won  = (const int*)d_in[17];

  float* out = (float*)d_out;
  float* emb = out;
  float* ctx = out + (size_t)NT * ND;

  int* ip         = (int*)d_ws;
  int* goRep      = ip;                    // 8 lines (8*32 ints)
  int* arr        = ip + 256;              // NB lines
  int* nLevels    = ip + 256 + NB * 32;
  int* dep0       = nLevels + 32;
  int* dep1       = dep0 + NG;
  int* level      = dep1 + NG;
  int* hist       = level + NG;
  int* cursor     = hist + NG;
  int* levelStart = cursor + NG;           // NG+2
  int* levelList  = levelStart + NG + 2;
  const int flagInts = 256 + NB * 32;
  size_t control = (size_t)((char*)(levelList + NG) - (char*)d_ws);
  control = (control + 255) & ~(size_t)255;

  int Wcap = WCAP;
  {
    size_t avail = (ws_size > control + 4096)
        ? (ws_size - control) / ((size_t)(1024 + 256) * sizeof(float))
        : 8;
    if (avail < (size_t)Wcap) Wcap = (int)avail;
    if (Wcap < 8) Wcap = 8;
  }
  float* nhbuf  = (float*)((char*)d_ws + control);
  float* hidbuf = nhbuf + (size_t)Wcap * 1024;

  hipMemcpyAsync(emb, emb_table, (size_t)NT * ND * sizeof(float),
                 hipMemcpyDeviceToDevice, stream);
  zero_kernel<<<(flagInts + 255) / 256, 256, 0, stream>>>(ip, flagInts);
  deps_kernel<<<(NG + 255) / 256, 256, 0, stream>>>(team_a, team_b, dep0, dep1);
  levels_kernel<<<1, 1024, 0, stream>>>(dep0, dep1, level, nLevels);
  sort_kernel<<<1, 1024, 0, stream>>>(level, nLevels, hist, cursor, levelStart, levelList);
  game_kernel<<<NB, BLK, 0, stream>>>(
      Wp, bp, W_ih, b_ih, W_hh, b_hh, ln_g, ln_b, Wi1, bi1, Wi2, bi2,
      fA, fB, team_a, team_b, a_won, emb, ctx,
      levelStart, levelList, nLevels, nhbuf, hidbuf, goRep, arr, Wcap);
}